// Round 5
// baseline (390.838 us; speedup 1.0000x reference)
//
#include <hip/hip_runtime.h>
#include <cstdio>

// ---------------- problem constants ----------------
constexpr int T  = 4096;       // B*S tokens
constexpr int D  = 1024;       // n_embed
constexpr int M  = 1408;       // n_moe_mlp
constexpr int E  = 8;          // experts

constexpr int TM = 128;        // token-rows per tile
constexpr int TN = 128;        // output cols per tile
constexpr int BK = 32;         // K-step
constexpr int RCAP = T * 2 + E * TM;  // 9216 padded row capacity
constexpr int MAX_TILES = RCAP / TM;  // 72
constexpr int NT_UP = M / TN;  // 11
constexpr int NT_DN = D / TN;  // 8

constexpr int CSTR = 64;       // per-expert counter stride in ints (256 B)
constexpr int TOKB = 64;       // tokens per router block

typedef _Float16 half8 __attribute__((ext_vector_type(8)));
typedef _Float16 half4 __attribute__((ext_vector_type(4)));
typedef float    floatx4 __attribute__((ext_vector_type(4)));

// ---------------- ws layout (bytes) ----------------
constexpr size_t OFF_COUNTS = 0;                               // E*CSTR ints
constexpr size_t OFF_BASE   = (size_t)E * CSTR * 4;            // E ints
constexpr size_t OFF_PC     = OFF_BASE + 64;                   // E ints
constexpr size_t OFF_TOTAL  = OFF_PC + 64;                     // 1 int
constexpr size_t OFF_WORK   = OFF_TOTAL + 64;                  // MAX_TILES ints
constexpr size_t OFF_NT     = OFF_WORK + 320;                  // 1 int
constexpr size_t OFF_T2E    = OFF_NT + 64;                     // 2T ints
constexpr size_t OFF_T2POS  = OFF_T2E   + (size_t)2 * T * 4;
constexpr size_t OFF_T2P    = OFF_T2POS + (size_t)2 * T * 4;
constexpr size_t OFF_TLIST  = OFF_T2P   + (size_t)2 * T * 4;   // E*T ints
constexpr size_t OFF_XG     = OFF_TLIST + (size_t)E * T * 4;   // RCAP x D fp16 (reused as Yp)
constexpr size_t OFF_HID    = OFF_XG  + (size_t)RCAP * D * 2;  // RCAP x M fp16
constexpr size_t OFF_WGT    = OFF_HID + (size_t)RCAP * M * 2;  // E x M x D fp16
constexpr size_t OFF_WUT    = OFF_WGT + (size_t)E * M * D * 2;
constexpr size_t OFF_WDT    = OFF_WUT + (size_t)E * M * D * 2; // E x D x M fp16
constexpr size_t WS_NEED    = OFF_WDT + (size_t)E * D * M * 2;

// async global->LDS, 16B per lane. LDS dest = wave-uniform base + lane*16.
__device__ __forceinline__ void gl_lds16(const void* g, void* l) {
  __builtin_amdgcn_global_load_lds(
      (const __attribute__((address_space(1))) unsigned int*)g,
      (__attribute__((address_space(3))) unsigned int*)l, 16, 0, 0);
}

// ---------------- router: 64 tokens/block, LDS-aggregated positions ----------------
__global__ __launch_bounds__(256) void k_router(
    const float* __restrict__ x, const float* __restrict__ wgate,
    int* __restrict__ counts, int* __restrict__ tlist,
    int* __restrict__ t2e, int* __restrict__ t2pos, float* __restrict__ t2p) {
  __shared__ int   s_cnt[E];
  __shared__ int   s_base[E];
  __shared__ int   s_e[2 * TOKB];
  __shared__ int   s_pos[2 * TOKB];
  __shared__ float s_p[2 * TOKB];
  int wv = threadIdx.x >> 6, lane = threadIdx.x & 63;
  if (threadIdx.x < E) s_cnt[threadIdx.x] = 0;
  __syncthreads();

  for (int j = 0; j < TOKB / 4; ++j) {
    int tl = wv * (TOKB / 4) + j;
    int t  = blockIdx.x * TOKB + tl;
    const float* xr = x + (size_t)t * D;
    float acc[E] = {0.f,0.f,0.f,0.f,0.f,0.f,0.f,0.f};
    #pragma unroll
    for (int i = 0; i < D / 64; ++i) {
      int d = i * 64 + lane;
      float xv = xr[d];
      const float4* wr2 = (const float4*)(wgate + (size_t)d * E);
      float4 w0 = wr2[0], w1 = wr2[1];
      acc[0] += xv * w0.x; acc[1] += xv * w0.y; acc[2] += xv * w0.z; acc[3] += xv * w0.w;
      acc[4] += xv * w1.x; acc[5] += xv * w1.y; acc[6] += xv * w1.z; acc[7] += xv * w1.w;
    }
    #pragma unroll
    for (int e = 0; e < E; ++e) {
      #pragma unroll
      for (int off = 32; off; off >>= 1) acc[e] += __shfl_xor(acc[e], off, 64);
    }
    if (lane == 0) {
      int i0 = 0; float s0 = acc[0];
      #pragma unroll
      for (int e = 1; e < E; ++e) if (acc[e] > s0) { s0 = acc[e]; i0 = e; }
      int i1 = -1; float s1 = -1e30f;
      #pragma unroll
      for (int e = 0; e < E; ++e) if (e != i0 && acc[e] > s1) { s1 = acc[e]; i1 = e; }
      float p0 = 1.f / (1.f + expf(s1 - s0));
      float p1 = 1.f - p0;
      int q0 = atomicAdd(&s_cnt[i0], 1);
      int q1 = atomicAdd(&s_cnt[i1], 1);
      s_e[2 * tl]     = i0; s_pos[2 * tl]     = q0; s_p[2 * tl]     = p0;
      s_e[2 * tl + 1] = i1; s_pos[2 * tl + 1] = q1; s_p[2 * tl + 1] = p1;
    }
  }
  __syncthreads();
  if (threadIdx.x < E)
    s_base[threadIdx.x] = atomicAdd(&counts[threadIdx.x * CSTR], s_cnt[threadIdx.x]);
  __syncthreads();
  if (threadIdx.x < 2 * TOKB) {
    int sl = threadIdx.x;
    int e = s_e[sl];
    int pos = s_base[e] + s_pos[sl];
    int t = blockIdx.x * TOKB + (sl >> 1);
    tlist[e * T + pos] = t;
    t2e[2 * t + (sl & 1)]   = e;
    t2pos[2 * t + (sl & 1)] = pos;
    t2p[2 * t + (sl & 1)]   = s_p[sl];
  }
}

// ---------------- scan + compacted tile work list ----------------
__global__ void k_scan(const int* __restrict__ counts, int* __restrict__ base,
                       int* __restrict__ pc, int* __restrict__ total,
                       int* __restrict__ work, int* __restrict__ ntiles) {
  if (threadIdx.x == 0 && blockIdx.x == 0) {
    int b = 0, w = 0;
    for (int e = 0; e < E; ++e) {
      base[e] = b;
      int p = (counts[e * CSTR] + TM - 1) / TM * TM;
      pc[e] = p;
      for (int i = 0; i < p / TM; ++i) work[w++] = (e << 16) | i;
      b += p;
    }
    *total = b;
    *ntiles = w;
  }
}

// ---------------- gather tokens -> fp16, zero pad rows ----------------
__global__ __launch_bounds__(256) void k_gather(
    const float* __restrict__ x, const int* __restrict__ counts,
    const int* __restrict__ base, const int* __restrict__ pc,
    const int* __restrict__ total, const int* __restrict__ tlist,
    _Float16* __restrict__ Xg) {
  int r = blockIdx.x;
  if (r >= *total) return;
  int e = 0;
  while (e < E - 1 && r >= base[e] + pc[e]) ++e;
  int local = r - base[e];
  int d = threadIdx.x * 4;
  union { _Float16 h[4]; ushort4 u; } o;
  if (local < counts[e * CSTR]) {
    int t = tlist[e * T + local];
    float4 v = *(const float4*)(x + (size_t)t * D + d);
    o.h[0] = (_Float16)v.x; o.h[1] = (_Float16)v.y;
    o.h[2] = (_Float16)v.z; o.h[3] = (_Float16)v.w;
  } else {
    o.h[0] = (_Float16)0.f; o.h[1] = (_Float16)0.f;
    o.h[2] = (_Float16)0.f; o.h[3] = (_Float16)0.f;
  }
  *(ushort4*)(Xg + (size_t)r * D + d) = o.u;
}

// ---------------- transpose-convert: [E][R][C] f32 -> [E][C][R] f16 ----------------
__global__ __launch_bounds__(256) void k_transpose(
    const float* __restrict__ src, _Float16* __restrict__ dst, int R, int C) {
  __shared__ float tile[32][33];
  int e = blockIdx.z, rt = blockIdx.y, ct = blockIdx.x;
  int tr  = threadIdx.x >> 3;
  int tc4 = (threadIdx.x & 7) * 4;
  const float* s = src + ((size_t)e * R + rt * 32 + tr) * C + ct * 32 + tc4;
  float4 v = *(const float4*)s;
  tile[tr][tc4 + 0] = v.x; tile[tr][tc4 + 1] = v.y;
  tile[tr][tc4 + 2] = v.z; tile[tr][tc4 + 3] = v.w;
  __syncthreads();
  union { _Float16 h[4]; ushort4 u; } o;
  #pragma unroll
  for (int i = 0; i < 4; ++i) o.h[i] = (_Float16)tile[tc4 + i][tr];
  *(ushort4*)(dst + ((size_t)e * C + ct * 32 + tr) * R + rt * 32 + tc4) = o.u;
}

// ---------------- fused gate+up grouped GEMM + SiLU ----------------
// Compacted work list (no dead/imbalanced blocks); double-buffered LDS with a
// single barrier per K-iter: loads for k+1 issue after the top barrier, the
// full compute phase of iter k hides their latency before the next drain.
__global__ __launch_bounds__(256, 2) void k_upgate(
    const _Float16* __restrict__ Xg, const _Float16* __restrict__ wgT,
    const _Float16* __restrict__ wuT, _Float16* __restrict__ Hid,
    const int* __restrict__ base, const int* __restrict__ work,
    const int* __restrict__ ntiles) {
  int nt = blockIdx.x % NT_UP;
  int wt = blockIdx.x / NT_UP;
  if (wt >= *ntiles) return;
  int packed = work[wt];
  int e = packed >> 16, mt = packed & 0xffff;
  int row0 = base[e] + mt * TM;
  int n0 = nt * TN;
  __shared__ _Float16 As[2][TM * BK];
  __shared__ _Float16 Bg[2][TN * BK];
  __shared__ _Float16 Bu[2][TN * BK];
  int tid = threadIdx.x;
  int w = tid >> 6, lane = tid & 63;
  int lrow = lane & 15, quad = lane >> 4;
  int wr = w >> 1, wc = w & 1;
  int sr = lane >> 2, sc = (lane & 3) * 8;
  int slot0 = (w * 2 + 0) * 1024, slot1 = (w * 2 + 1) * 1024;  // byte offsets

  const _Float16* wg_e = wgT + (size_t)e * M * D;
  const _Float16* wu_e = wuT + (size_t)e * M * D;
  const _Float16* pA0 = Xg + (size_t)(row0 + w * 32 + sr) * D + sc;
  const _Float16* pA1 = Xg + (size_t)(row0 + w * 32 + 16 + sr) * D + sc;
  const _Float16* pG0 = wg_e + (size_t)(n0 + w * 32 + sr) * D + sc;
  const _Float16* pG1 = wg_e + (size_t)(n0 + w * 32 + 16 + sr) * D + sc;
  const _Float16* pU0 = wu_e + (size_t)(n0 + w * 32 + sr) * D + sc;
  const _Float16* pU1 = wu_e + (size_t)(n0 + w * 32 + 16 + sr) * D + sc;

  floatx4 accg[4][4] = {};   // [c][i]
  floatx4 accu[4][4] = {};

  auto issue6 = [&](int p) {
    char* a = (char*)As[p]; char* g = (char*)Bg[p]; char* u = (char*)Bu[p];
    gl_lds16(pA0, a + slot0); gl_lds16(pA1, a + slot1);
    gl_lds16(pG0, g + slot0); gl_lds16(pG1, g + slot1);
    gl_lds16(pU0, u + slot0); gl_lds16(pU1, u + slot1);
    pA0 += BK; pA1 += BK; pG0 += BK; pG1 += BK; pU0 += BK; pU1 += BK;
  };

  constexpr int NIT = D / BK;   // 32
  issue6(0);
  int p = 0;
  for (int it = 0; it < NIT; ++it) {
    __syncthreads();                    // drains loads -> buf[p] ready; fences prior reads
    if (it + 1 < NIT) issue6(p ^ 1);    // prefetch next tile, latency hidden by compute below
    half8 af[4];
    #pragma unroll
    for (int i = 0; i < 4; ++i)
      af[i] = *(const half8*)&As[p][(wr * 64 + i * 16 + lrow) * BK + quad * 8];
    #pragma unroll
    for (int c = 0; c < 4; ++c) {
      half8 bgc = *(const half8*)&Bg[p][(wc * 64 + c * 16 + lrow) * BK + quad * 8];
      half8 buc = *(const half8*)&Bu[p][(wc * 64 + c * 16 + lrow) * BK + quad * 8];
      #pragma unroll
      for (int i = 0; i < 4; ++i) {
        accg[c][i] = __builtin_amdgcn_mfma_f32_16x16x32_f16(af[i], bgc, accg[c][i], 0, 0, 0);
        accu[c][i] = __builtin_amdgcn_mfma_f32_16x16x32_f16(af[i], buc, accu[c][i], 0, 0, 0);
      }
    }
    p ^= 1;
  }
  #pragma unroll
  for (int c = 0; c < 4; ++c) {
    int col = n0 + wc * 64 + c * 16 + lrow;
    #pragma unroll
    for (int i = 0; i < 4; ++i) {
      int rowb = row0 + wr * 64 + i * 16 + quad * 4;
      #pragma unroll
      for (int reg = 0; reg < 4; ++reg) {
        float g = accg[c][i][reg], u = accu[c][i][reg];
        Hid[(size_t)(rowb + reg) * M + col] = (_Float16)(g / (1.f + expf(-g)) * u);
      }
    }
  }
}

// ---------------- down grouped GEMM -> per-slot rows Yp ----------------
__global__ __launch_bounds__(256, 2) void k_down(
    const _Float16* __restrict__ Hid, const _Float16* __restrict__ wdT,
    _Float16* __restrict__ Yp,
    const int* __restrict__ base, const int* __restrict__ work,
    const int* __restrict__ ntiles) {
  int nt = blockIdx.x % NT_DN;
  int wt = blockIdx.x / NT_DN;
  if (wt >= *ntiles) return;
  int packed = work[wt];
  int e = packed >> 16, mt = packed & 0xffff;
  int row0 = base[e] + mt * TM;
  int d0 = nt * TN;
  __shared__ _Float16 As[2][TM * BK];
  __shared__ _Float16 Bs[2][TN * BK];
  int tid = threadIdx.x;
  int w = tid >> 6, lane = tid & 63;
  int lrow = lane & 15, quad = lane >> 4;
  int wr = w >> 1, wc = w & 1;
  int sr = lane >> 2, sc = (lane & 3) * 8;
  int slot0 = (w * 2 + 0) * 1024, slot1 = (w * 2 + 1) * 1024;

  const _Float16* wd_e = wdT + (size_t)e * D * M;
  const _Float16* pA0 = Hid + (size_t)(row0 + w * 32 + sr) * M + sc;
  const _Float16* pA1 = Hid + (size_t)(row0 + w * 32 + 16 + sr) * M + sc;
  const _Float16* pB0 = wd_e + (size_t)(d0 + w * 32 + sr) * M + sc;
  const _Float16* pB1 = wd_e + (size_t)(d0 + w * 32 + 16 + sr) * M + sc;

  floatx4 acc[4][4] = {};

  auto issue4 = [&](int p) {
    char* a = (char*)As[p]; char* b = (char*)Bs[p];
    gl_lds16(pA0, a + slot0); gl_lds16(pA1, a + slot1);
    gl_lds16(pB0, b + slot0); gl_lds16(pB1, b + slot1);
    pA0 += BK; pA1 += BK; pB0 += BK; pB1 += BK;
  };

  constexpr int NIT = M / BK;   // 44
  issue4(0);
  int p = 0;
  for (int it = 0; it < NIT; ++it) {
    __syncthreads();
    if (it + 1 < NIT) issue4(p ^ 1);
    half8 af[4];
    #pragma unroll
    for (int i = 0; i < 4; ++i)
      af[i] = *(const half8*)&As[p][(wr * 64 + i * 16 + lrow) * BK + quad * 8];
    #pragma unroll
    for (int c = 0; c < 4; ++c) {
      half8 bc = *(const half8*)&Bs[p][(wc * 64 + c * 16 + lrow) * BK + quad * 8];
      #pragma unroll
      for (int i = 0; i < 4; ++i)
        acc[c][i] = __builtin_amdgcn_mfma_f32_16x16x32_f16(af[i], bc, acc[c][i], 0, 0, 0);
    }
    p ^= 1;
  }
  #pragma unroll
  for (int c = 0; c < 4; ++c) {
    int col = d0 + wc * 64 + c * 16 + lrow;
    #pragma unroll
    for (int i = 0; i < 4; ++i) {
      int rowb = row0 + wr * 64 + i * 16 + quad * 4;
      #pragma unroll
      for (int reg = 0; reg < 4; ++reg)
        Yp[(size_t)(rowb + reg) * D + col] = (_Float16)acc[c][i][reg];
    }
  }
}

// ---------------- combine: y[t] = p0*Yp[r0] + p1*Yp[r1] ----------------
__global__ __launch_bounds__(256) void k_combine(
    const _Float16* __restrict__ Yp, const int* __restrict__ base,
    const int* __restrict__ t2e, const int* __restrict__ t2pos,
    const float* __restrict__ t2p, float* __restrict__ out) {
  int t = blockIdx.x;
  int r0 = base[t2e[2 * t]]     + t2pos[2 * t];
  int r1 = base[t2e[2 * t + 1]] + t2pos[2 * t + 1];
  float p0 = t2p[2 * t], p1 = t2p[2 * t + 1];
  int d = threadIdx.x * 4;
  half4 h0 = *(const half4*)(Yp + (size_t)r0 * D + d);
  half4 h1 = *(const half4*)(Yp + (size_t)r1 * D + d);
  float4 o;
  o.x = p0 * (float)h0.x + p1 * (float)h1.x;
  o.y = p0 * (float)h0.y + p1 * (float)h1.y;
  o.z = p0 * (float)h0.z + p1 * (float)h1.z;
  o.w = p0 * (float)h0.w + p1 * (float)h1.w;
  *(float4*)(out + (size_t)t * D + d) = o;
}

// ---------------- launch ----------------
extern "C" void kernel_launch(void* const* d_in, const int* in_sizes, int n_in,
                              void* d_out, int out_size, void* d_ws, size_t ws_size,
                              hipStream_t stream) {
  const float* x     = (const float*)d_in[0];
  const float* wgate = (const float*)d_in[1];
  const float* w_g   = (const float*)d_in[2];
  const float* w_u   = (const float*)d_in[3];
  const float* w_d   = (const float*)d_in[4];
  float* out = (float*)d_out;
  char* ws = (char*)d_ws;

  if (ws_size < WS_NEED) {
    fprintf(stderr, "kernel_launch: ws_size=%zu < needed %zu\n", ws_size, WS_NEED);
    return;
  }

  int* counts = (int*)(ws + OFF_COUNTS);
  int* base   = (int*)(ws + OFF_BASE);
  int* pcn    = (int*)(ws + OFF_PC);
  int* total  = (int*)(ws + OFF_TOTAL);
  int* work   = (int*)(ws + OFF_WORK);
  int* ntiles = (int*)(ws + OFF_NT);
  int* t2e    = (int*)(ws + OFF_T2E);
  int* t2pos  = (int*)(ws + OFF_T2POS);
  float* t2p  = (float*)(ws + OFF_T2P);
  int* tlist  = (int*)(ws + OFF_TLIST);
  _Float16* Xg  = (_Float16*)(ws + OFF_XG);   // later reused as Yp
  _Float16* Hid = (_Float16*)(ws + OFF_HID);
  _Float16* wgT = (_Float16*)(ws + OFF_WGT);
  _Float16* wuT = (_Float16*)(ws + OFF_WUT);
  _Float16* wdT = (_Float16*)(ws + OFF_WDT);

  hipMemsetAsync(ws, 0, OFF_T2E, stream);

  k_router<<<T / TOKB, 256, 0, stream>>>(x, wgate, counts, tlist, t2e, t2pos, t2p);
  k_scan<<<1, 64, 0, stream>>>(counts, base, pcn, total, work, ntiles);
  k_gather<<<RCAP, 256, 0, stream>>>(x, counts, base, pcn, total, tlist, Xg);

  k_transpose<<<dim3(M / 32, D / 32, E), 256, 0, stream>>>(w_g, wgT, D, M);
  k_transpose<<<dim3(M / 32, D / 32, E), 256, 0, stream>>>(w_u, wuT, D, M);
  k_transpose<<<dim3(D / 32, M / 32, E), 256, 0, stream>>>(w_d, wdT, M, D);

  k_upgate<<<MAX_TILES * NT_UP, 256, 0, stream>>>(Xg, wgT, wuT, Hid, base, work, ntiles);
  _Float16* Yp = Xg;   // Xg dead; reuse as Yp
  k_down<<<MAX_TILES * NT_DN, 256, 0, stream>>>(Hid, wdT, Yp, base, work, ntiles);
  k_combine<<<T, 256, 0, stream>>>(Yp, base, t2e, t2pos, t2p, out);
}

// Round 6
// 361.665 us; speedup vs baseline: 1.0807x; 1.0807x over previous
//
#include <hip/hip_runtime.h>
#include <cstdio>

// ---------------- problem constants ----------------
constexpr int T  = 4096;       // B*S tokens
constexpr int D  = 1024;       // n_embed
constexpr int M  = 1408;       // n_moe_mlp
constexpr int E  = 8;          // experts

constexpr int TM = 128;        // token-rows per tile
constexpr int TN = 128;        // output cols per tile
constexpr int BK = 32;         // K-step
constexpr int RCAP = T * 2 + E * TM;  // 9216 padded row capacity
constexpr int MAX_TILES = RCAP / TM;  // 72
constexpr int NT_UP = M / TN;  // 11
constexpr int NT_DN = D / TN;  // 8
constexpr int MAXW_UP = MAX_TILES * NT_UP;  // 792
constexpr int MAXW_DN = MAX_TILES * NT_DN;  // 576

constexpr int CSTR = 64;       // per-expert counter stride in ints (256 B)
constexpr int TOKB = 64;       // tokens per router block

typedef _Float16 half8 __attribute__((ext_vector_type(8)));
typedef _Float16 half4 __attribute__((ext_vector_type(4)));
typedef float    floatx4 __attribute__((ext_vector_type(4)));

// ---------------- ws layout (bytes) ----------------
constexpr size_t OFF_COUNTS = 0;                               // E*CSTR ints
constexpr size_t OFF_BASE   = (size_t)E * CSTR * 4;            // 2048
constexpr size_t OFF_PC     = OFF_BASE + 64;
constexpr size_t OFF_TOTAL  = OFF_PC + 64;
constexpr size_t OFF_NWU    = OFF_TOTAL + 64;
constexpr size_t OFF_NWD    = OFF_NWU + 64;
constexpr size_t OFF_WUP    = OFF_NWD + 64;                    // MAXW_UP ints
constexpr size_t OFF_WDN    = OFF_WUP + (size_t)MAXW_UP * 4;   // MAXW_DN ints
constexpr size_t OFF_T2E    = (OFF_WDN + (size_t)MAXW_DN * 4 + 63) & ~(size_t)63;
constexpr size_t OFF_T2POS  = OFF_T2E   + (size_t)2 * T * 4;
constexpr size_t OFF_T2P    = OFF_T2POS + (size_t)2 * T * 4;
constexpr size_t OFF_TLIST  = OFF_T2P   + (size_t)2 * T * 4;   // E*T ints
constexpr size_t OFF_XG     = OFF_TLIST + (size_t)E * T * 4;   // RCAP x D fp16 (reused as Yp)
constexpr size_t OFF_HID    = OFF_XG  + (size_t)RCAP * D * 2;  // RCAP x M fp16
constexpr size_t OFF_WGT    = OFF_HID + (size_t)RCAP * M * 2;  // E x M x D fp16
constexpr size_t OFF_WUT    = OFF_WGT + (size_t)E * M * D * 2;
constexpr size_t OFF_WDT    = OFF_WUT + (size_t)E * M * D * 2; // E x D x M fp16
constexpr size_t WS_NEED    = OFF_WDT + (size_t)E * D * M * 2;

// async global->LDS, 16B per lane. LDS dest = wave-uniform base + lane*16.
__device__ __forceinline__ void gl_lds16(const void* g, void* l) {
  __builtin_amdgcn_global_load_lds(
      (const __attribute__((address_space(1))) unsigned int*)g,
      (__attribute__((address_space(3))) unsigned int*)l, 16, 0, 0);
}

// ---------------- router: 64 tokens/block, LDS-aggregated positions ----------------
__global__ __launch_bounds__(256) void k_router(
    const float* __restrict__ x, const float* __restrict__ wgate,
    int* __restrict__ counts, int* __restrict__ tlist,
    int* __restrict__ t2e, int* __restrict__ t2pos, float* __restrict__ t2p) {
  __shared__ int   s_cnt[E];
  __shared__ int   s_base[E];
  __shared__ int   s_e[2 * TOKB];
  __shared__ int   s_pos[2 * TOKB];
  __shared__ float s_p[2 * TOKB];
  int wv = threadIdx.x >> 6, lane = threadIdx.x & 63;
  if (threadIdx.x < E) s_cnt[threadIdx.x] = 0;
  __syncthreads();

  for (int j = 0; j < TOKB / 4; ++j) {
    int tl = wv * (TOKB / 4) + j;
    int t  = blockIdx.x * TOKB + tl;
    const float* xr = x + (size_t)t * D;
    float acc[E] = {0.f,0.f,0.f,0.f,0.f,0.f,0.f,0.f};
    #pragma unroll
    for (int i = 0; i < D / 64; ++i) {
      int d = i * 64 + lane;
      float xv = xr[d];
      const float4* wr2 = (const float4*)(wgate + (size_t)d * E);
      float4 w0 = wr2[0], w1 = wr2[1];
      acc[0] += xv * w0.x; acc[1] += xv * w0.y; acc[2] += xv * w0.z; acc[3] += xv * w0.w;
      acc[4] += xv * w1.x; acc[5] += xv * w1.y; acc[6] += xv * w1.z; acc[7] += xv * w1.w;
    }
    #pragma unroll
    for (int e = 0; e < E; ++e) {
      #pragma unroll
      for (int off = 32; off; off >>= 1) acc[e] += __shfl_xor(acc[e], off, 64);
    }
    if (lane == 0) {
      int i0 = 0; float s0 = acc[0];
      #pragma unroll
      for (int e = 1; e < E; ++e) if (acc[e] > s0) { s0 = acc[e]; i0 = e; }
      int i1 = -1; float s1 = -1e30f;
      #pragma unroll
      for (int e = 0; e < E; ++e) if (e != i0 && acc[e] > s1) { s1 = acc[e]; i1 = e; }
      float p0 = 1.f / (1.f + expf(s1 - s0));
      float p1 = 1.f - p0;
      int q0 = atomicAdd(&s_cnt[i0], 1);
      int q1 = atomicAdd(&s_cnt[i1], 1);
      s_e[2 * tl]     = i0; s_pos[2 * tl]     = q0; s_p[2 * tl]     = p0;
      s_e[2 * tl + 1] = i1; s_pos[2 * tl + 1] = q1; s_p[2 * tl + 1] = p1;
    }
  }
  __syncthreads();
  if (threadIdx.x < E)
    s_base[threadIdx.x] = atomicAdd(&counts[threadIdx.x * CSTR], s_cnt[threadIdx.x]);
  __syncthreads();
  if (threadIdx.x < 2 * TOKB) {
    int sl = threadIdx.x;
    int e = s_e[sl];
    int pos = s_base[e] + s_pos[sl];
    int t = blockIdx.x * TOKB + (sl >> 1);
    tlist[e * T + pos] = t;
    t2e[2 * t + (sl & 1)]   = e;
    t2pos[2 * t + (sl & 1)] = pos;
    t2p[2 * t + (sl & 1)]   = s_p[sl];
  }
}

// ---------------- scan + flattened (e, nt, mt) work lists ----------------
__global__ __launch_bounds__(256) void k_scan(
    const int* __restrict__ counts, int* __restrict__ base,
    int* __restrict__ pc, int* __restrict__ total,
    int* __restrict__ wup, int* __restrict__ nwu,
    int* __restrict__ wdn, int* __restrict__ nwd) {
  __shared__ int sp[E], su[E + 1], sd[E + 1];
  if (threadIdx.x == 0) {
    int b = 0; su[0] = 0; sd[0] = 0;
    for (int e = 0; e < E; ++e) {
      base[e] = b;
      int p = (counts[e * CSTR] + TM - 1) / TM * TM;
      pc[e] = p; sp[e] = p; b += p;
      int nt_tiles = p / TM;
      su[e + 1] = su[e] + nt_tiles * NT_UP;
      sd[e + 1] = sd[e] + nt_tiles * NT_DN;
    }
    *total = b;
    *nwu = su[E];
    *nwd = sd[E];
  }
  __syncthreads();
  int nu = su[E], nd = sd[E];
  for (int i = threadIdx.x; i < nu; i += blockDim.x) {
    int e = 0;
    while (i >= su[e + 1]) ++e;
    int tiles = sp[e] / TM;
    int loc = i - su[e];
    int nt = loc / tiles, mt = loc % tiles;   // nt-major: consecutive i share B(e,nt)
    wup[i] = (e << 20) | (nt << 10) | mt;
  }
  for (int i = threadIdx.x; i < nd; i += blockDim.x) {
    int e = 0;
    while (i >= sd[e + 1]) ++e;
    int tiles = sp[e] / TM;
    int loc = i - sd[e];
    int nt = loc / tiles, mt = loc % tiles;
    wdn[i] = (e << 20) | (nt << 10) | mt;
  }
}

// ---------------- gather tokens -> fp16, zero pad rows ----------------
__global__ __launch_bounds__(256) void k_gather(
    const float* __restrict__ x, const int* __restrict__ counts,
    const int* __restrict__ base, const int* __restrict__ pc,
    const int* __restrict__ total, const int* __restrict__ tlist,
    _Float16* __restrict__ Xg) {
  int r = blockIdx.x;
  if (r >= *total) return;
  int e = 0;
  while (e < E - 1 && r >= base[e] + pc[e]) ++e;
  int local = r - base[e];
  int d = threadIdx.x * 4;
  union { _Float16 h[4]; ushort4 u; } o;
  if (local < counts[e * CSTR]) {
    int t = tlist[e * T + local];
    float4 v = *(const float4*)(x + (size_t)t * D + d);
    o.h[0] = (_Float16)v.x; o.h[1] = (_Float16)v.y;
    o.h[2] = (_Float16)v.z; o.h[3] = (_Float16)v.w;
  } else {
    o.h[0] = (_Float16)0.f; o.h[1] = (_Float16)0.f;
    o.h[2] = (_Float16)0.f; o.h[3] = (_Float16)0.f;
  }
  *(ushort4*)(Xg + (size_t)r * D + d) = o.u;
}

// ---------------- transpose-convert: [E][R][C] f32 -> [E][C][R] f16 ----------------
__global__ __launch_bounds__(256) void k_transpose(
    const float* __restrict__ src, _Float16* __restrict__ dst, int R, int C) {
  __shared__ float tile[32][33];
  int e = blockIdx.z, rt = blockIdx.y, ct = blockIdx.x;
  int tr  = threadIdx.x >> 3;
  int tc4 = (threadIdx.x & 7) * 4;
  const float* s = src + ((size_t)e * R + rt * 32 + tr) * C + ct * 32 + tc4;
  float4 v = *(const float4*)s;
  tile[tr][tc4 + 0] = v.x; tile[tr][tc4 + 1] = v.y;
  tile[tr][tc4 + 2] = v.z; tile[tr][tc4 + 3] = v.w;
  __syncthreads();
  union { _Float16 h[4]; ushort4 u; } o;
  #pragma unroll
  for (int i = 0; i < 4; ++i) o.h[i] = (_Float16)tile[tc4 + i][tr];
  *(ushort4*)(dst + ((size_t)e * C + ct * 32 + tr) * R + rt * 32 + tc4) = o.u;
}

// XCD-chunked work decode: round-robin dispatch (block i -> XCD i&7) means
// XCD x executes work items [x*nchunk, (x+1)*nchunk) — a CONTIGUOUS run of the
// (e, nt, mt) space, so B(e,nt) tiles and one expert's A rows stay in that
// XCD's L2. Seam overlaps recompute identical values (benign). Balanced chunks.
__device__ __forceinline__ int xcd_wid(int nw) {
  int nchunk = (nw + 7) >> 3;
  return (blockIdx.x & 7) * nchunk + (blockIdx.x >> 3);
}

// ---------------- fused gate+up grouped GEMM + SiLU ----------------
__global__ __launch_bounds__(256, 2) void k_upgate(
    const _Float16* __restrict__ Xg, const _Float16* __restrict__ wgT,
    const _Float16* __restrict__ wuT, _Float16* __restrict__ Hid,
    const int* __restrict__ base, const int* __restrict__ wlist,
    const int* __restrict__ nwork) {
  int nw = *nwork;
  int wid = xcd_wid(nw);
  if (wid >= nw) return;
  int packed = wlist[wid];
  int e = packed >> 20, nt = (packed >> 10) & 1023, mt = packed & 1023;
  int row0 = base[e] + mt * TM;
  int n0 = nt * TN;
  __shared__ _Float16 As[2][TM * BK];
  __shared__ _Float16 Bg[2][TN * BK];
  __shared__ _Float16 Bu[2][TN * BK];
  int tid = threadIdx.x;
  int w = tid >> 6, lane = tid & 63;
  int lrow = lane & 15, quad = lane >> 4;
  int wr = w >> 1, wc = w & 1;
  int sr = lane >> 2, sc = (lane & 3) * 8;
  int slot0 = (w * 2 + 0) * 1024, slot1 = (w * 2 + 1) * 1024;  // byte offsets

  const _Float16* wg_e = wgT + (size_t)e * M * D;
  const _Float16* wu_e = wuT + (size_t)e * M * D;
  const _Float16* pA0 = Xg + (size_t)(row0 + w * 32 + sr) * D + sc;
  const _Float16* pA1 = Xg + (size_t)(row0 + w * 32 + 16 + sr) * D + sc;
  const _Float16* pG0 = wg_e + (size_t)(n0 + w * 32 + sr) * D + sc;
  const _Float16* pG1 = wg_e + (size_t)(n0 + w * 32 + 16 + sr) * D + sc;
  const _Float16* pU0 = wu_e + (size_t)(n0 + w * 32 + sr) * D + sc;
  const _Float16* pU1 = wu_e + (size_t)(n0 + w * 32 + 16 + sr) * D + sc;

  floatx4 accg[4][4] = {};   // [c][i]
  floatx4 accu[4][4] = {};

  auto issue6 = [&](int p) {
    char* a = (char*)As[p]; char* g = (char*)Bg[p]; char* u = (char*)Bu[p];
    gl_lds16(pA0, a + slot0); gl_lds16(pA1, a + slot1);
    gl_lds16(pG0, g + slot0); gl_lds16(pG1, g + slot1);
    gl_lds16(pU0, u + slot0); gl_lds16(pU1, u + slot1);
    pA0 += BK; pA1 += BK; pG0 += BK; pG1 += BK; pU0 += BK; pU1 += BK;
  };

  constexpr int NIT = D / BK;   // 32
  issue6(0);
  int p = 0;
  for (int it = 0; it < NIT; ++it) {
    __syncthreads();                    // buf[p] ready; prior reads fenced
    if (it + 1 < NIT) issue6(p ^ 1);    // prefetch next tile under compute
    half8 af[4];
    #pragma unroll
    for (int i = 0; i < 4; ++i)
      af[i] = *(const half8*)&As[p][(wr * 64 + i * 16 + lrow) * BK + quad * 8];
    #pragma unroll
    for (int c = 0; c < 4; ++c) {
      half8 bgc = *(const half8*)&Bg[p][(wc * 64 + c * 16 + lrow) * BK + quad * 8];
      half8 buc = *(const half8*)&Bu[p][(wc * 64 + c * 16 + lrow) * BK + quad * 8];
      #pragma unroll
      for (int i = 0; i < 4; ++i) {
        accg[c][i] = __builtin_amdgcn_mfma_f32_16x16x32_f16(af[i], bgc, accg[c][i], 0, 0, 0);
        accu[c][i] = __builtin_amdgcn_mfma_f32_16x16x32_f16(af[i], buc, accu[c][i], 0, 0, 0);
      }
    }
    p ^= 1;
  }
  #pragma unroll
  for (int c = 0; c < 4; ++c) {
    int col = n0 + wc * 64 + c * 16 + lrow;
    #pragma unroll
    for (int i = 0; i < 4; ++i) {
      int rowb = row0 + wr * 64 + i * 16 + quad * 4;
      #pragma unroll
      for (int reg = 0; reg < 4; ++reg) {
        float g = accg[c][i][reg], u = accu[c][i][reg];
        Hid[(size_t)(rowb + reg) * M + col] = (_Float16)(g / (1.f + expf(-g)) * u);
      }
    }
  }
}

// ---------------- down grouped GEMM -> per-slot rows Yp ----------------
__global__ __launch_bounds__(256, 2) void k_down(
    const _Float16* __restrict__ Hid, const _Float16* __restrict__ wdT,
    _Float16* __restrict__ Yp,
    const int* __restrict__ base, const int* __restrict__ wlist,
    const int* __restrict__ nwork) {
  int nw = *nwork;
  int wid = xcd_wid(nw);
  if (wid >= nw) return;
  int packed = wlist[wid];
  int e = packed >> 20, nt = (packed >> 10) & 1023, mt = packed & 1023;
  int row0 = base[e] + mt * TM;
  int d0 = nt * TN;
  __shared__ _Float16 As[2][TM * BK];
  __shared__ _Float16 Bs[2][TN * BK];
  int tid = threadIdx.x;
  int w = tid >> 6, lane = tid & 63;
  int lrow = lane & 15, quad = lane >> 4;
  int wr = w >> 1, wc = w & 1;
  int sr = lane >> 2, sc = (lane & 3) * 8;
  int slot0 = (w * 2 + 0) * 1024, slot1 = (w * 2 + 1) * 1024;

  const _Float16* wd_e = wdT + (size_t)e * D * M;
  const _Float16* pA0 = Hid + (size_t)(row0 + w * 32 + sr) * M + sc;
  const _Float16* pA1 = Hid + (size_t)(row0 + w * 32 + 16 + sr) * M + sc;
  const _Float16* pB0 = wd_e + (size_t)(d0 + w * 32 + sr) * M + sc;
  const _Float16* pB1 = wd_e + (size_t)(d0 + w * 32 + 16 + sr) * M + sc;

  floatx4 acc[4][4] = {};

  auto issue4 = [&](int p) {
    char* a = (char*)As[p]; char* b = (char*)Bs[p];
    gl_lds16(pA0, a + slot0); gl_lds16(pA1, a + slot1);
    gl_lds16(pB0, b + slot0); gl_lds16(pB1, b + slot1);
    pA0 += BK; pA1 += BK; pB0 += BK; pB1 += BK;
  };

  constexpr int NIT = M / BK;   // 44
  issue4(0);
  int p = 0;
  for (int it = 0; it < NIT; ++it) {
    __syncthreads();
    if (it + 1 < NIT) issue4(p ^ 1);
    half8 af[4];
    #pragma unroll
    for (int i = 0; i < 4; ++i)
      af[i] = *(const half8*)&As[p][(wr * 64 + i * 16 + lrow) * BK + quad * 8];
    #pragma unroll
    for (int c = 0; c < 4; ++c) {
      half8 bc = *(const half8*)&Bs[p][(wc * 64 + c * 16 + lrow) * BK + quad * 8];
      #pragma unroll
      for (int i = 0; i < 4; ++i)
        acc[c][i] = __builtin_amdgcn_mfma_f32_16x16x32_f16(af[i], bc, acc[c][i], 0, 0, 0);
    }
    p ^= 1;
  }
  #pragma unroll
  for (int c = 0; c < 4; ++c) {
    int col = d0 + wc * 64 + c * 16 + lrow;
    #pragma unroll
    for (int i = 0; i < 4; ++i) {
      int rowb = row0 + wr * 64 + i * 16 + quad * 4;
      #pragma unroll
      for (int reg = 0; reg < 4; ++reg)
        Yp[(size_t)(rowb + reg) * D + col] = (_Float16)acc[c][i][reg];
    }
  }
}

// ---------------- combine: y[t] = p0*Yp[r0] + p1*Yp[r1] ----------------
__global__ __launch_bounds__(256) void k_combine(
    const _Float16* __restrict__ Yp, const int* __restrict__ base,
    const int* __restrict__ t2e, const int* __restrict__ t2pos,
    const float* __restrict__ t2p, float* __restrict__ out) {
  int t = blockIdx.x;
  int r0 = base[t2e[2 * t]]     + t2pos[2 * t];
  int r1 = base[t2e[2 * t + 1]] + t2pos[2 * t + 1];
  float p0 = t2p[2 * t], p1 = t2p[2 * t + 1];
  int d = threadIdx.x * 4;
  half4 h0 = *(const half4*)(Yp + (size_t)r0 * D + d);
  half4 h1 = *(const half4*)(Yp + (size_t)r1 * D + d);
  float4 o;
  o.x = p0 * (float)h0.x + p1 * (float)h1.x;
  o.y = p0 * (float)h0.y + p1 * (float)h1.y;
  o.z = p0 * (float)h0.z + p1 * (float)h1.z;
  o.w = p0 * (float)h0.w + p1 * (float)h1.w;
  *(float4*)(out + (size_t)t * D + d) = o;
}

// ---------------- launch ----------------
extern "C" void kernel_launch(void* const* d_in, const int* in_sizes, int n_in,
                              void* d_out, int out_size, void* d_ws, size_t ws_size,
                              hipStream_t stream) {
  const float* x     = (const float*)d_in[0];
  const float* wgate = (const float*)d_in[1];
  const float* w_g   = (const float*)d_in[2];
  const float* w_u   = (const float*)d_in[3];
  const float* w_d   = (const float*)d_in[4];
  float* out = (float*)d_out;
  char* ws = (char*)d_ws;

  if (ws_size < WS_NEED) {
    fprintf(stderr, "kernel_launch: ws_size=%zu < needed %zu\n", ws_size, WS_NEED);
    return;
  }

  int* counts = (int*)(ws + OFF_COUNTS);
  int* base   = (int*)(ws + OFF_BASE);
  int* pcn    = (int*)(ws + OFF_PC);
  int* total  = (int*)(ws + OFF_TOTAL);
  int* nwu    = (int*)(ws + OFF_NWU);
  int* nwd    = (int*)(ws + OFF_NWD);
  int* wup    = (int*)(ws + OFF_WUP);
  int* wdn    = (int*)(ws + OFF_WDN);
  int* t2e    = (int*)(ws + OFF_T2E);
  int* t2pos  = (int*)(ws + OFF_T2POS);
  float* t2p  = (float*)(ws + OFF_T2P);
  int* tlist  = (int*)(ws + OFF_TLIST);
  _Float16* Xg  = (_Float16*)(ws + OFF_XG);   // later reused as Yp
  _Float16* Hid = (_Float16*)(ws + OFF_HID);
  _Float16* wgT = (_Float16*)(ws + OFF_WGT);
  _Float16* wuT = (_Float16*)(ws + OFF_WUT);
  _Float16* wdT = (_Float16*)(ws + OFF_WDT);

  hipMemsetAsync(ws, 0, OFF_T2E, stream);

  k_router<<<T / TOKB, 256, 0, stream>>>(x, wgate, counts, tlist, t2e, t2pos, t2p);
  k_scan<<<1, 256, 0, stream>>>(counts, base, pcn, total, wup, nwu, wdn, nwd);
  k_gather<<<RCAP, 256, 0, stream>>>(x, counts, base, pcn, total, tlist, Xg);

  k_transpose<<<dim3(M / 32, D / 32, E), 256, 0, stream>>>(w_g, wgT, D, M);
  k_transpose<<<dim3(M / 32, D / 32, E), 256, 0, stream>>>(w_u, wuT, D, M);
  k_transpose<<<dim3(D / 32, M / 32, E), 256, 0, stream>>>(w_d, wdT, M, D);

  k_upgate<<<MAXW_UP, 256, 0, stream>>>(Xg, wgT, wuT, Hid, base, wup, nwu);
  _Float16* Yp = Xg;   // Xg dead; reuse as Yp
  k_down<<<MAXW_DN, 256, 0, stream>>>(Hid, wdT, Yp, base, wdn, nwd);
  k_combine<<<T, 256, 0, stream>>>(Yp, base, t2e, t2pos, t2p, out);
}